// Round 3
// baseline (19.983 us; speedup 1.0000x reference)
//
#include <hip/hip_runtime.h>

#define EPS 1e-5f

// Geometry: inp (25,2,128,8,8) fp32 -> 3200 (n,s) instances, hw=64, c=2.
// InstanceNorm over (c,hw)=128; qkv = y @ qkv_w^T + b (192 rows);
// linear attn collapses (c=2) to 2x2 M = q k^T, attn = v + M v;
// out = attn @ proj_w^T + proj_b + inp.  Output fp32.
//
// Block = 256 threads (4 waves), 4 instances/block, 800 blocks:
//  A: wave w -> instance w (wave-shuffle norm)
//  B: threads 0..191 each own one qkv output row (row t of qkv_w),
//     computing it for all 4 instances x 2 channels -> LDS
//  C: wave w -> 2x2 M for instance w via shuffle reduce, attn -> LDS
//  D: thread r -> (instance r>>6 == wave, col r&63): proj dot + residual

__global__ __launch_bounds__(256)
void attn_fused(const float* __restrict__ inp,
                const float* __restrict__ qkv_w,
                const float* __restrict__ qkv_b,
                const float* __restrict__ proj_w,
                const float* __restrict__ proj_b,
                float* __restrict__ out)
{
    const int tid = threadIdx.x;
    const int w   = tid >> 6;              // wave id == instance slot 0..3
    const int t   = tid & 63;              // lane
    const int g   = blockIdx.x * 4 + w;    // global instance (never crosses n: 128%4==0)
    const int n   = g >> 7;
    const int s   = g & 127;

    __shared__ float y_lds[4][2][64];        // normalized input
    __shared__ float qkv_lds[3][4][2][64];   // [q/k/v][inst][chan][col]
    __shared__ float a_lds[4][2][64];        // attn output

    // ---------------- Phase A: load + InstanceNorm (per wave) ----------------
    // flat idx: n*16384 + c*8192 + s*64 + j
    const int base = n * 16384 + s * 64 + t;
    const float x0 = inp[base];
    const float x1 = inp[base + 8192];
    float s1 = x0 + x1;
    float s2 = fmaf(x0, x0, x1 * x1);
    #pragma unroll
    for (int m = 32; m >= 1; m >>= 1) {
        s1 += __shfl_xor(s1, m);
        s2 += __shfl_xor(s2, m);
    }
    const float mean = s1 * (1.0f / 128.0f);
    const float var  = s2 * (1.0f / 128.0f) - mean * mean;   // biased, like jnp.var
    const float rs   = rsqrtf(var + EPS);
    y_lds[w][0][t] = (x0 - mean) * rs;
    y_lds[w][1][t] = (x1 - mean) * rs;
    __syncthreads();

    // ---------------- Phase B: qkv rows (threads 0..191) ----------------
    if (tid < 192) {
        float acc[4][2] = {{0.f,0.f},{0.f,0.f},{0.f,0.f},{0.f,0.f}};
        const float4* wr = reinterpret_cast<const float4*>(qkv_w + tid * 64);
        #pragma unroll 4
        for (int j4 = 0; j4 < 16; ++j4) {
            const float4 wv = wr[j4];
            #pragma unroll
            for (int i = 0; i < 4; ++i) {
                #pragma unroll
                for (int c = 0; c < 2; ++c) {
                    const float4 y = *reinterpret_cast<const float4*>(&y_lds[i][c][j4 * 4]);
                    acc[i][c] = fmaf(wv.x, y.x, fmaf(wv.y, y.y,
                                fmaf(wv.z, y.z, fmaf(wv.w, y.w, acc[i][c]))));
                }
            }
        }
        const float b   = qkv_b[tid];
        const int   sel = tid >> 6;     // 0=q, 1=k, 2=v
        const int   col = tid & 63;
        #pragma unroll
        for (int i = 0; i < 4; ++i) {
            #pragma unroll
            for (int c = 0; c < 2; ++c) {
                qkv_lds[sel][i][c][col] = acc[i][c] + b;
            }
        }
    }
    __syncthreads();

    // ---------------- Phase C: 2x2 M + attn (wave w -> instance w) ----------------
    const float q0 = qkv_lds[0][w][0][t], q1 = qkv_lds[0][w][1][t];
    const float k0 = qkv_lds[1][w][0][t], k1 = qkv_lds[1][w][1][t];
    const float v0 = qkv_lds[2][w][0][t], v1 = qkv_lds[2][w][1][t];
    float p0 = q0 * k0, p1 = q0 * k1, p2 = q1 * k0, p3 = q1 * k1;
    #pragma unroll
    for (int m = 32; m >= 1; m >>= 1) {
        p0 += __shfl_xor(p0, m);
        p1 += __shfl_xor(p1, m);
        p2 += __shfl_xor(p2, m);
        p3 += __shfl_xor(p3, m);
    }
    a_lds[w][0][t] = v0 + fmaf(p0, v0, p1 * v1);
    a_lds[w][1][t] = v1 + fmaf(p2, v0, p3 * v1);
    __syncthreads();

    // ---------------- Phase D: proj + residual + store ----------------
    // thread r: instance i = r>>6 (== w), output col = r&63 (== t)
    float ao0 = 0.f, ao1 = 0.f;
    const float4* pr = reinterpret_cast<const float4*>(proj_w + t * 64);
    #pragma unroll 4
    for (int j4 = 0; j4 < 16; ++j4) {
        const float4 wv = pr[j4];
        const float4 a0 = *reinterpret_cast<const float4*>(&a_lds[w][0][j4 * 4]);
        const float4 a1 = *reinterpret_cast<const float4*>(&a_lds[w][1][j4 * 4]);
        ao0 = fmaf(wv.x, a0.x, fmaf(wv.y, a0.y, fmaf(wv.z, a0.z, fmaf(wv.w, a0.w, ao0))));
        ao1 = fmaf(wv.x, a1.x, fmaf(wv.y, a1.y, fmaf(wv.z, a1.z, fmaf(wv.w, a1.w, ao1))));
    }
    const float pb = proj_b[t];
    out[base]        = ao0 + pb + x0;
    out[base + 8192] = ao1 + pb + x1;
}

extern "C" void kernel_launch(void* const* d_in, const int* in_sizes, int n_in,
                              void* d_out, int out_size, void* d_ws, size_t ws_size,
                              hipStream_t stream) {
    const float* inp    = (const float*)d_in[0];
    const float* qkv_w  = (const float*)d_in[1];
    const float* qkv_b  = (const float*)d_in[2];
    const float* proj_w = (const float*)d_in[3];
    const float* proj_b = (const float*)d_in[4];
    float* out = (float*)d_out;

    attn_fused<<<dim3(800), dim3(256), 0, stream>>>(inp, qkv_w, qkv_b, proj_w, proj_b, out);
}